// Round 8
// baseline (31843.661 us; speedup 1.0000x reference)
//
#include <hip/hip_runtime.h>
#include <hip/hip_bf16.h>

#define Bq 64
#define Tq 512
#define Eq 128
#define Hq 256
#define NTAGS 50
#define Mq (Bq*Tq)   // 32768

__device__ __forceinline__ float sigmoidf_(float x) { return 1.f / (1.f + expf(-x)); }

// ---------------- dtype detection: int32 vs int64 for words/lengths ----------------
__global__ void detect_int64(const unsigned* __restrict__ words,
                             const unsigned* __restrict__ lens,
                             unsigned* __restrict__ dflags) {
    __shared__ int wbad, lbad, wnz, lnz;
    if (threadIdx.x == 0) { wbad = 0; lbad = 0; wnz = 0; lnz = 0; }
    __syncthreads();
    for (int i = threadIdx.x; i < 16384; i += blockDim.x) {
        if (words[2 * i + 1] != 0u) wbad = 1;
        if (words[2 * i] != 0u) wnz = 1;
    }
    for (int i = threadIdx.x; i < 32; i += blockDim.x) {
        if (lens[2 * i + 1] != 0u) lbad = 1;
        if (lens[2 * i] != 0u) lnz = 1;
    }
    __syncthreads();
    if (threadIdx.x == 0) {
        unsigned f = 0;
        if (!wbad && wnz) f |= 1u;
        if (!lbad && lnz) f |= 2u;
        dflags[0] = f;
    }
}

// ---------------- bias: bias[l][d][n] = bih + bhh ----------------
__global__ void bias_kernel(const float* b1f_ih, const float* b1f_hh,
                            const float* b1b_ih, const float* b1b_hh,
                            const float* b2f_ih, const float* b2f_hh,
                            const float* b2b_ih, const float* b2b_hh,
                            float* bias) {   // [4][1024]: l1f,l1b,l2f,l2b
    int i = blockIdx.x * blockDim.x + threadIdx.x;
    if (i >= 4096) return;
    int l = i >> 11, d = (i >> 10) & 1, nn = i & 1023;
    float v;
    if (l == 0) v = d ? (b1b_ih[nn] + b1b_hh[nn]) : (b1f_ih[nn] + b1f_hh[nn]);
    else        v = d ? (b2b_ih[nn] + b2b_hh[nn]) : (b2f_ih[nn] + b2f_hh[nn]);
    bias[i] = v;
}

// ---------------- f32 GEMM: C[M,N] = A[M,K] @ W[N,K]^T + bias ----------------
// AMODE: 0 = A f32, 2 = A gathered from emb via words (dtype-adaptive), 3 = A f16
// OUTT:  0 = f32, 1 = f16
template<int AMODE, int OUTT>
__global__ __launch_bounds__(256)
void gemm_kernel(const void* __restrict__ Aptr, const unsigned* __restrict__ words_u32,
                 const float* __restrict__ emb, const unsigned* __restrict__ dflags,
                 const float* __restrict__ Wlo, const float* __restrict__ Whi,
                 const float* __restrict__ blo, const float* __restrict__ bhi,
                 void* __restrict__ Cptr, int M, int N, int K)
{
    __shared__ float As[16][68];
    __shared__ float Ws[16][68];
    const int tx = threadIdx.x & 15, ty = threadIdx.x >> 4;
    const int m0 = blockIdx.y * 64, n0 = blockIdx.x * 64;
    const bool hi = ((m0 & 511) >= 256);
    const float* W = hi ? Whi : Wlo;
    const float* bias = hi ? bhi : blo;
    const int lr = threadIdx.x >> 2, lc = threadIdx.x & 3;
    bool w64 = false;
    if (AMODE == 2) w64 = (dflags[0] & 1u) != 0u;
    float acc[4][4] = {};
    for (int k0 = 0; k0 < K; k0 += 16) {
        float a4[4], w4[4];
        if (AMODE == 2) {
            int m = m0 + lr;
            int w = (int)(w64 ? words_u32[2 * m] : words_u32[m]);
            float4 v = *(const float4*)(emb + (size_t)w * Eq + k0 + lc * 4);
            a4[0] = v.x; a4[1] = v.y; a4[2] = v.z; a4[3] = v.w;
        } else if (AMODE == 0) {
            float4 v = *(const float4*)((const float*)Aptr + (size_t)(m0 + lr) * K + k0 + lc * 4);
            a4[0] = v.x; a4[1] = v.y; a4[2] = v.z; a4[3] = v.w;
        } else {
            const _Float16* Ab = (const _Float16*)Aptr + (size_t)(m0 + lr) * K + k0 + lc * 4;
            #pragma unroll
            for (int q = 0; q < 4; ++q) a4[q] = (float)Ab[q];
        }
        int nrow = n0 + lr;
        if (nrow < N) {
            float4 v = *(const float4*)(W + (size_t)nrow * K + k0 + lc * 4);
            w4[0] = v.x; w4[1] = v.y; w4[2] = v.z; w4[3] = v.w;
        } else { w4[0] = w4[1] = w4[2] = w4[3] = 0.f; }
        __syncthreads();
        #pragma unroll
        for (int q = 0; q < 4; ++q) {
            As[lc * 4 + q][lr] = a4[q];
            Ws[lc * 4 + q][lr] = w4[q];
        }
        __syncthreads();
        #pragma unroll
        for (int kk = 0; kk < 16; ++kk) {
            float4 a = *(const float4*)&As[kk][ty * 4];
            float4 w = *(const float4*)&Ws[kk][tx * 4];
            float av[4] = {a.x, a.y, a.z, a.w};
            float wv[4] = {w.x, w.y, w.z, w.w};
            #pragma unroll
            for (int i = 0; i < 4; ++i)
                #pragma unroll
                for (int j = 0; j < 4; ++j)
                    acc[i][j] += av[i] * wv[j];
        }
    }
    #pragma unroll
    for (int i = 0; i < 4; ++i) {
        int row = m0 + ty * 4 + i;
        #pragma unroll
        for (int j = 0; j < 4; ++j) {
            int col = n0 + tx * 4 + j;
            if (col < N) {
                float v = acc[i][j] + bias[col];
                if (OUTT == 1) ((_Float16*)Cptr)[(size_t)row * N + col] = (_Float16)v;
                else           ((float*)Cptr)[(size_t)row * N + col] = v;
            }
        }
    }
}

// ---------------- simple zero-exchange LSTM: 1 block per (dir, b) ----------------
template<int OUTT>
__global__ __launch_bounds__(512)
void lstm_simple(const float* __restrict__ xg,
                 const float* __restrict__ Whh_f,
                 const float* __restrict__ Whh_b,
                 const unsigned* __restrict__ len_u32,
                 const unsigned* __restrict__ dflags,
                 float* __restrict__ Hsav,
                 float* __restrict__ Csav,
                 void* __restrict__ out,
                 int t0, int t1)
{
    __shared__ float hsh[256];
    __shared__ float red[8][256];

    const int tid = threadIdx.x;
    const int j = tid & 255, half = tid >> 8;
    const int bid = blockIdx.x;
    const int dir = bid & 1, b = bid >> 1;
    const float* __restrict__ Whh = dir ? Whh_b : Whh_f;
    const bool l64 = (dflags[0] & 2u) != 0u;
    const int mylen = (int)(l64 ? len_u32[2 * b] : len_u32[b]);
    const int kb = half * 128;

    float c = 0.f;
    if (tid < 256) {
        if (t0 == 0) {
            hsh[j] = 0.f;
        } else {
            c = Csav[((size_t)dir * Bq + b) * Hq + j];
            hsh[j] = Hsav[((size_t)dir * Bq + b) * Hq + j];
        }
    }
    __syncthreads();

    const float* __restrict__ W0 = Whh + (size_t)(0 * 256 + j) * 256 + kb;
    const float* __restrict__ W1 = Whh + (size_t)(1 * 256 + j) * 256 + kb;
    const float* __restrict__ W2 = Whh + (size_t)(2 * 256 + j) * 256 + kb;
    const float* __restrict__ W3 = Whh + (size_t)(3 * 256 + j) * 256 + kb;

    for (int t = t0; t < t1; ++t) {
        const int teff = dir ? (Tq - 1 - t) : t;
        float a0 = 0.f, a1 = 0.f, a2 = 0.f, a3 = 0.f;
        #pragma unroll 4
        for (int k = 0; k < 128; k += 4) {
            float4 hv = *(const float4*)(hsh + kb + k);
            float4 w0 = *(const float4*)(W0 + k);
            float4 w1 = *(const float4*)(W1 + k);
            float4 w2 = *(const float4*)(W2 + k);
            float4 w3 = *(const float4*)(W3 + k);
            a0 += w0.x * hv.x + w0.y * hv.y + w0.z * hv.z + w0.w * hv.w;
            a1 += w1.x * hv.x + w1.y * hv.y + w1.z * hv.z + w1.w * hv.w;
            a2 += w2.x * hv.x + w2.y * hv.y + w2.z * hv.z + w2.w * hv.w;
            a3 += w3.x * hv.x + w3.y * hv.y + w3.z * hv.z + w3.w * hv.w;
        }
        red[0 * 2 + half][j] = a0;
        red[1 * 2 + half][j] = a1;
        red[2 * 2 + half][j] = a2;
        red[3 * 2 + half][j] = a3;
        __syncthreads();
        if (tid < 256) {
            const float* xrow = xg + ((size_t)b * Tq + teff) * 1024;
            float g0 = xrow[0 * 256 + j] + red[0][j] + red[1][j];
            float g1 = xrow[1 * 256 + j] + red[2][j] + red[3][j];
            float g2 = xrow[2 * 256 + j] + red[4][j] + red[5][j];
            float g3 = xrow[3 * 256 + j] + red[6][j] + red[7][j];
            float ig = sigmoidf_(g0);
            float fg = sigmoidf_(g1);
            float gg = tanhf(g2);
            float og = sigmoidf_(g3);
            float cn = fg * c + ig * gg;
            float hn = og * tanhf(cn);
            bool m = (teff < mylen);
            float hold = hsh[j];
            float hm = m ? hn : hold;
            c = m ? cn : c;
            hsh[j] = hm;
            size_t orow = (size_t)b * Tq + teff;
            if (OUTT == 1) ((_Float16*)out)[orow * 512 + dir * 256 + j] = (_Float16)hm;
            else           ((float*)out)[orow * 512 + dir * 256 + j] = hm;
        }
        __syncthreads();
    }
    if (tid < 256) {
        Csav[((size_t)dir * Bq + b) * Hq + j] = c;
        Hsav[((size_t)dir * Bq + b) * Hq + j] = hsh[j];
    }
}

extern "C" void kernel_launch(void* const* d_in, const int* in_sizes, int n_in,
                              void* d_out, int out_size, void* d_ws, size_t ws_size,
                              hipStream_t stream)
{
    const unsigned* words  = (const unsigned*)d_in[0];
    const unsigned* lens   = (const unsigned*)d_in[1];
    const float* emb     = (const float*)d_in[2];
    const float* l1f_Wih = (const float*)d_in[3];
    const float* l1f_Whh = (const float*)d_in[4];
    const float* l1f_bih = (const float*)d_in[5];
    const float* l1f_bhh = (const float*)d_in[6];
    const float* l1b_Wih = (const float*)d_in[7];
    const float* l1b_Whh = (const float*)d_in[8];
    const float* l1b_bih = (const float*)d_in[9];
    const float* l1b_bhh = (const float*)d_in[10];
    const float* l2f_Wih = (const float*)d_in[11];
    const float* l2f_Whh = (const float*)d_in[12];
    const float* l2f_bih = (const float*)d_in[13];
    const float* l2f_bhh = (const float*)d_in[14];
    const float* l2b_Wih = (const float*)d_in[15];
    const float* l2b_Whh = (const float*)d_in[16];
    const float* l2b_bih = (const float*)d_in[17];
    const float* l2b_bhh = (const float*)d_in[18];
    const float* cls_W   = (const float*)d_in[19];
    const float* cls_b   = (const float*)d_in[20];
    (void)in_sizes; (void)n_in; (void)out_size; (void)ws_size;

    char* ws = (char*)d_ws;
    size_t off = 0;
    auto alloc = [&](size_t b) { void* p = ws + off; off += (b + 255) & ~(size_t)255; return p; };
    float*     xg = (float*)alloc((size_t)Mq * 1024 * 4);   // 128 MiB, reused 4x
    float*     o1 = (float*)alloc((size_t)Mq * 512 * 4);    // 64 MiB
    _Float16*  o2 = (_Float16*)alloc((size_t)Mq * 512 * 2); // 32 MiB
    float*   Hsav = (float*)alloc((size_t)2 * Bq * Hq * 4);
    float*   Csav = (float*)alloc((size_t)2 * Bq * Hq * 4);
    float* biasbuf = (float*)alloc((size_t)4 * 1024 * 4);
    unsigned* dflags = (unsigned*)alloc(256);

    const float* b1f = biasbuf, *b1b = biasbuf + 1024, *b2f = biasbuf + 2048, *b2b = biasbuf + 3072;

    detect_int64<<<1, 256, 0, stream>>>(words, lens, dflags);
    bias_kernel<<<dim3(16), 256, 0, stream>>>(l1f_bih, l1f_bhh, l1b_bih, l1b_bhh,
                                              l2f_bih, l2f_bhh, l2b_bih, l2b_bhh, biasbuf);

    dim3 ggrid(1024 / 64, Mq / 64);
    // ---- layer 1 ----
    gemm_kernel<2, 0><<<ggrid, 256, 0, stream>>>(nullptr, words, emb, dflags,
        l1f_Wih, l1b_Wih, b1f, b1b, xg, Mq, 1024, Eq);
    lstm_simple<0><<<128, 512, 0, stream>>>(xg, l1f_Whh, l1b_Whh, lens, dflags, Hsav, Csav, o1, 0, 256);
    gemm_kernel<2, 0><<<ggrid, 256, 0, stream>>>(nullptr, words, emb, dflags,
        l1b_Wih, l1f_Wih, b1b, b1f, xg, Mq, 1024, Eq);
    lstm_simple<0><<<128, 512, 0, stream>>>(xg, l1f_Whh, l1b_Whh, lens, dflags, Hsav, Csav, o1, 256, 512);
    // ---- layer 2 ----
    gemm_kernel<0, 0><<<ggrid, 256, 0, stream>>>(o1, nullptr, nullptr, dflags,
        l2f_Wih, l2b_Wih, b2f, b2b, xg, Mq, 1024, 512);
    lstm_simple<1><<<128, 512, 0, stream>>>(xg, l2f_Whh, l2b_Whh, lens, dflags, Hsav, Csav, o2, 0, 256);
    gemm_kernel<0, 0><<<ggrid, 256, 0, stream>>>(o1, nullptr, nullptr, dflags,
        l2b_Wih, l2f_Wih, b2b, b2f, xg, Mq, 1024, 512);
    lstm_simple<1><<<128, 512, 0, stream>>>(xg, l2f_Whh, l2b_Whh, lens, dflags, Hsav, Csav, o2, 256, 512);
    // ---- classifier -> d_out (FLOAT32: reference output dtype) ----
    gemm_kernel<3, 0><<<dim3(1, Mq / 64), 256, 0, stream>>>(o2, nullptr, nullptr, dflags,
        cls_W, cls_W, cls_b, cls_b, d_out, Mq, NTAGS, 512);
}